// Round 1
// baseline (377.040 us; speedup 1.0000x reference)
//
#include <hip/hip_runtime.h>

// irreps linear: 256x0e + 128x1o + 64x2e, shared weights, bias on 0e.
// x: (200000, 960) f32; w: 86016 f32; b: 256 f32; out: (200000, 960) f32.
//
// Strategy: bf16 MFMA (16x16x32), weights pre-packed into fragment-ready
// layout in d_ws by a prep kernel (pre-scaled by path_weight). One wave
// owns 16 rows x 960 cols; A-frags built from global fp32 + cvt; B-frags
// are coalesced 16B/lane loads from ws (L2-hot). No LDS, no barriers.

typedef short frag8 __attribute__((ext_vector_type(8)));   // 8 bf16
typedef float f32x4 __attribute__((ext_vector_type(4)));

static __device__ __forceinline__ short f2bf(float f) {
    union { float f; unsigned u; } v; v.f = f;
    unsigned r = (v.u + 0x7FFFu + ((v.u >> 16) & 1u)) >> 16;  // RNE
    return (short)r;
}

#define MFMA(a, b, c) __builtin_amdgcn_mfma_f32_16x16x32_bf16((a), (b), (c), 0, 0, 0)

// ---- weight prep: w (f32, 86016) -> fragment-ready bf16 in ws ----
// frag f, lane l, reg j holds B[k][n] with k = 32*s + 4*(l>>4) + (j&3) + 16*(j>>2),
// n = nt*16 + (l&15).  (Any bijective (lg,j)->k map works as long as the A side
// uses the same one -- k is contracted.)
// frag ids: block0: f = nt*8 + s (128 frags); block1: 128 + nt*4 + s (32);
//           block2: 160 + nt*2 + s (8).  Total 168 frags * 512 bf16 = 86016.
__global__ __launch_bounds__(256) void prep_kernel(const float* __restrict__ w,
                                                   short* __restrict__ wf) {
    int e = blockIdx.x * 256 + threadIdx.x;   // 0..86015
    int f = e >> 9;
    int r = e & 511;
    int l = r >> 3, j = r & 7;
    int l15 = l & 15, lg = l >> 4;
    int kk = 4 * lg + (j & 3) + 16 * (j >> 2);   // k within 32-window
    int u, wc, woff, mul; float scale;
    if (f < 128) {
        int nt = f >> 3, s = f & 7;
        u = 32 * s + kk; wc = nt * 16 + l15; woff = 0;     mul = 256; scale = 0.0625f;
    } else if (f < 160) {
        int g = f - 128, nt = g >> 2, s = g & 3;
        u = 32 * s + kk; wc = nt * 16 + l15; woff = 65536; mul = 128; scale = 0.088388347648318447f;
    } else {
        int g = f - 160, nt = g >> 1, s = g & 1;
        u = 32 * s + kk; wc = nt * 16 + l15; woff = 81920; mul = 64;  scale = 0.125f;
    }
    wf[e] = f2bf(scale * w[woff + u * mul + wc]);
}

// ---- main kernel: 4 independent waves per block, 16 rows per wave ----
__global__ __launch_bounds__(256) void lin_main(const float* __restrict__ x,
                                                const short* __restrict__ wf,
                                                const float* __restrict__ bias,
                                                float* __restrict__ out) {
    const int lane = threadIdx.x & 63;
    const int wv   = threadIdx.x >> 6;
    const int l15  = lane & 15;
    const int lg   = lane >> 4;
    const long row0 = ((long)blockIdx.x * 4 + wv) * 16;
    const float* __restrict__ xr   = x   + row0 * 960;
    float* __restrict__       outr = out + row0 * 960;
    const frag8* __restrict__ wfr  = (const frag8*)wf;

    // ================= block 0 : cols 0..255, K=256 =================
    frag8 a0[8];
    {
        const float* p = xr + l15 * 960 + 4 * lg;
        #pragma unroll
        for (int s = 0; s < 8; ++s) {
            const float4 v0 = *(const float4*)(p + 32 * s);
            const float4 v1 = *(const float4*)(p + 32 * s + 16);
            frag8 a;
            a[0] = f2bf(v0.x); a[1] = f2bf(v0.y); a[2] = f2bf(v0.z); a[3] = f2bf(v0.w);
            a[4] = f2bf(v1.x); a[5] = f2bf(v1.y); a[6] = f2bf(v1.z); a[7] = f2bf(v1.w);
            a0[s] = a;
        }
    }
    #pragma unroll 4
    for (int nt = 0; nt < 16; ++nt) {
        f32x4 acc = {0.f, 0.f, 0.f, 0.f};
        #pragma unroll
        for (int s = 0; s < 8; ++s) {
            frag8 bf = wfr[(nt * 8 + s) * 64 + lane];
            acc = MFMA(a0[s], bf, acc);
        }
        const float bb = bias[nt * 16 + l15];
        #pragma unroll
        for (int j = 0; j < 4; ++j)
            outr[(4 * lg + j) * 960 + nt * 16 + l15] = acc[j] + bb;
    }

    // ================= block 1 : cols 256..639 (u,i interleave i-stride 1) ===
    // A for fixed i: k=u, x col = 256 + 3*u + i  (stride-3 scalar gathers)
    frag8 a1[12];
    #pragma unroll
    for (int i = 0; i < 3; ++i) {
        #pragma unroll
        for (int s = 0; s < 4; ++s) {
            const float* p = xr + l15 * 960 + 256 + i + 3 * (32 * s + 4 * lg);
            frag8 a;
            #pragma unroll
            for (int jj = 0; jj < 4; ++jj) a[jj]     = f2bf(p[3 * jj]);
            #pragma unroll
            for (int jj = 0; jj < 4; ++jj) a[4 + jj] = f2bf(p[48 + 3 * jj]);
            a1[i * 4 + s] = a;
        }
    }
    #pragma unroll 2
    for (int nt = 0; nt < 8; ++nt) {
        f32x4 c0 = {0.f,0.f,0.f,0.f}, c1 = {0.f,0.f,0.f,0.f}, c2 = {0.f,0.f,0.f,0.f};
        #pragma unroll
        for (int s = 0; s < 4; ++s) {
            frag8 bf = wfr[(128 + nt * 4 + s) * 64 + lane];
            c0 = MFMA(a1[0 + s], bf, c0);
            c1 = MFMA(a1[4 + s], bf, c1);
            c2 = MFMA(a1[8 + s], bf, c2);
        }
        const int cb = 256 + (nt * 16 + l15) * 3;
        #pragma unroll
        for (int j = 0; j < 4; ++j) {
            float* o = outr + (4 * lg + j) * 960 + cb;
            o[0] = c0[j]; o[1] = c1[j]; o[2] = c2[j];
        }
    }

    // ================= block 2 : cols 640..959 =================
    frag8 a2[10];
    #pragma unroll
    for (int i = 0; i < 5; ++i) {
        #pragma unroll
        for (int s = 0; s < 2; ++s) {
            const float* p = xr + l15 * 960 + 640 + i + 5 * (32 * s + 4 * lg);
            frag8 a;
            #pragma unroll
            for (int jj = 0; jj < 4; ++jj) a[jj]     = f2bf(p[5 * jj]);
            #pragma unroll
            for (int jj = 0; jj < 4; ++jj) a[4 + jj] = f2bf(p[80 + 5 * jj]);
            a2[i * 2 + s] = a;
        }
    }
    #pragma unroll 2
    for (int nt = 0; nt < 4; ++nt) {
        f32x4 c0 = {0.f,0.f,0.f,0.f}, c1 = {0.f,0.f,0.f,0.f}, c2 = {0.f,0.f,0.f,0.f},
              c3 = {0.f,0.f,0.f,0.f}, c4 = {0.f,0.f,0.f,0.f};
        #pragma unroll
        for (int s = 0; s < 2; ++s) {
            frag8 bf = wfr[(160 + nt * 2 + s) * 64 + lane];
            c0 = MFMA(a2[0 + s], bf, c0);
            c1 = MFMA(a2[2 + s], bf, c1);
            c2 = MFMA(a2[4 + s], bf, c2);
            c3 = MFMA(a2[6 + s], bf, c3);
            c4 = MFMA(a2[8 + s], bf, c4);
        }
        const int cb = 640 + (nt * 16 + l15) * 5;
        #pragma unroll
        for (int j = 0; j < 4; ++j) {
            float* o = outr + (4 * lg + j) * 960 + cb;
            o[0] = c0[j]; o[1] = c1[j]; o[2] = c2[j]; o[3] = c3[j]; o[4] = c4[j];
        }
    }
}

extern "C" void kernel_launch(void* const* d_in, const int* in_sizes, int n_in,
                              void* d_out, int out_size, void* d_ws, size_t ws_size,
                              hipStream_t stream) {
    const float* x = (const float*)d_in[0];
    const float* w = (const float*)d_in[1];
    const float* b = (const float*)d_in[2];
    float* out = (float*)d_out;
    short* wf  = (short*)d_ws;          // 86016 bf16 = 172032 B of scratch

    // pack weights (86016 elems / 256 = 336 blocks) -- runs every launch,
    // so the 0xAA ws poison is always overwritten.
    hipLaunchKernelGGL(prep_kernel, dim3(336), dim3(256), 0, stream, w, wf);
    // 200000 rows = 3125 blocks * 4 waves * 16 rows, exact.
    hipLaunchKernelGGL(lin_main, dim3(3125), dim3(256), 0, stream, x, wf, b, out);
}